// Round 1
// baseline (8373.887 us; speedup 1.0000x reference)
//
#include <hip/hip_runtime.h>
#include <stdint.h>

typedef _Float16 half8 __attribute__((ext_vector_type(8)));
typedef float f32x4 __attribute__((ext_vector_type(4)));

static constexpr int BN_ = 64;    // batch
static constexpr int TT_ = 512;   // time steps
static constexpr int II_ = 256;   // input dim
static constexpr int HH_ = 512;   // hidden dim
static constexpr int GG_ = 2048;  // 4*H
static constexpr int OO_ = 256;   // output dim

// workspace layout (bytes)
static constexpr size_t GX_OFF     = 0;
static constexpr size_t GX_BYTES   = (size_t)TT_ * BN_ * GG_ * 2;   // 128 MiB, fp16 [t][b][g']
static constexpr size_t HALL_OFF   = GX_OFF + GX_BYTES;
static constexpr size_t HALL_BYTES = (size_t)BN_ * TT_ * HH_ * 2;   // 32 MiB, fp16 [b][t][u]
static constexpr size_t HX_OFF     = HALL_OFF + HALL_BYTES;
static constexpr size_t HX_BYTES   = (size_t)2 * BN_ * HH_ * 2;     // h exchange, double buffered
static constexpr size_t FLAG_OFF   = HX_OFF + HX_BYTES;
static constexpr size_t FLAG_BYTES = (size_t)64 * 128;              // one 128B slot per block
static constexpr size_t WS_NEEDED  = FLAG_OFF + FLAG_BYTES;

__device__ __forceinline__ float sigm(float x)  { return 1.0f / (1.0f + __expf(-x)); }
__device__ __forceinline__ float tanha(float x) { return 1.0f - 2.0f / (__expf(2.0f * x) + 1.0f); }

__device__ __forceinline__ half8 cvt8(float4 a, float4 b) {
  half8 r;
  r[0]=(_Float16)a.x; r[1]=(_Float16)a.y; r[2]=(_Float16)a.z; r[3]=(_Float16)a.w;
  r[4]=(_Float16)b.x; r[5]=(_Float16)b.y; r[6]=(_Float16)b.z; r[7]=(_Float16)b.w;
  return r;
}

// ---------------------------------------------------------------------------
// Kernel 1: gates_x[t][b][g'] = (x @ W_ih.T)[b,t,R(g')] + b_ih[R] + b_hh[R]
// g' = 4*u + gate (permuted so the recurrence's 4 gates of unit u are adjacent)
// R(g') = (g'&3)*512 + (g'>>2)  (original row in W_ih / biases)
// M=32768 (m=b*512+t), N=2048, K=256. 128x128 tile, BK=32, 4 waves.
// ---------------------------------------------------------------------------
__global__ __launch_bounds__(256) void gates_gemm_k(
    const float* __restrict__ x, const float* __restrict__ Wih,
    const float* __restrict__ bih, const float* __restrict__ bhh,
    _Float16* __restrict__ gx)
{
  __shared__ _Float16 As[128][40];  // [m][k] fp16, +8 pad
  __shared__ _Float16 Bs[128][40];  // [n][k] fp16 (B transposed), +8 pad
  const int bn = blockIdx.x & 15;
  const int bm = blockIdx.x >> 4;
  const int M0 = bm * 128, N0 = bn * 128;
  const int tid = threadIdx.x;
  const int w = tid >> 6, l = tid & 63, lg = l >> 4, ln = l & 15;
  const int wm = w & 1, wn = w >> 1;
  const int sr = tid >> 1, sp = tid & 1;  // staging row / half-row
  const int nglob = N0 + sr;
  const int Rrow = (nglob & 3) * HH_ + (nglob >> 2);

  f32x4 acc[4][4];
  #pragma unroll
  for (int i = 0; i < 4; i++) {
    #pragma unroll
    for (int j = 0; j < 4; j++) acc[i][j] = (f32x4){0.f, 0.f, 0.f, 0.f};
  }

  for (int K0 = 0; K0 < II_; K0 += 32) {
    __syncthreads();
    {
      const float* s0 = x + (size_t)(M0 + sr) * II_ + K0 + sp * 16;
      float4 f0 = ((const float4*)s0)[0], f1 = ((const float4*)s0)[1];
      float4 f2 = ((const float4*)s0)[2], f3 = ((const float4*)s0)[3];
      *(half8*)&As[sr][sp * 16]     = cvt8(f0, f1);
      *(half8*)&As[sr][sp * 16 + 8] = cvt8(f2, f3);
      const float* s1 = Wih + (size_t)Rrow * II_ + K0 + sp * 16;
      float4 g0 = ((const float4*)s1)[0], g1 = ((const float4*)s1)[1];
      float4 g2 = ((const float4*)s1)[2], g3 = ((const float4*)s1)[3];
      *(half8*)&Bs[sr][sp * 16]     = cvt8(g0, g1);
      *(half8*)&Bs[sr][sp * 16 + 8] = cvt8(g2, g3);
    }
    __syncthreads();
    half8 af[4], bf[4];
    #pragma unroll
    for (int i = 0; i < 4; i++) af[i] = *(const half8*)&As[wm * 64 + i * 16 + ln][lg * 8];
    #pragma unroll
    for (int j = 0; j < 4; j++) bf[j] = *(const half8*)&Bs[wn * 64 + j * 16 + ln][lg * 8];
    #pragma unroll
    for (int i = 0; i < 4; i++) {
      #pragma unroll
      for (int j = 0; j < 4; j++)
        acc[i][j] = __builtin_amdgcn_mfma_f32_16x16x32_f16(af[i], bf[j], acc[i][j], 0, 0, 0);
    }
  }

  #pragma unroll
  for (int j = 0; j < 4; j++) {
    const int ncol = N0 + wn * 64 + j * 16 + ln;
    const int R = (ncol & 3) * HH_ + (ncol >> 2);
    const float bias = bih[R] + bhh[R];
    #pragma unroll
    for (int i = 0; i < 4; i++) {
      #pragma unroll
      for (int rr = 0; rr < 4; rr++) {
        const int m = M0 + wm * 64 + i * 16 + lg * 4 + rr;
        const int bb = m >> 9, tt = m & 511;  // m = b*512 + t
        gx[(size_t)tt * (BN_ * GG_) + (size_t)bb * GG_ + ncol] =
            (_Float16)(acc[i][j][rr] + bias);
      }
    }
  }
}

// ---------------------------------------------------------------------------
// Kernel 2: persistent LSTM recurrence.
// 64 blocks = 4 batch-groups (16 batches each) x 16 unit-slices (32 units each).
// W_hh fragments resident in VGPRs. Per step: spin on partner flags,
// acquire fence, 32 MFMA (G.T = Wsl * h.T), lane-local cell update,
// release fence, flag store. h exchange is parity double-buffered.
// ---------------------------------------------------------------------------
__global__ __launch_bounds__(256, 1) void lstm_rec_k(
    const float* __restrict__ Whh, const _Float16* __restrict__ gx,
    _Float16* __restrict__ hall, _Float16* __restrict__ hx,
    int* __restrict__ flags)
{
  const int bid = blockIdx.x;
  const int mg = bid >> 4, nb = bid & 15;
  const int tid = threadIdx.x;
  const int w = tid >> 6, l = tid & 63, lg = l >> 4, ln = l & 15;
  const int batch = mg * 16 + ln;

  // Preload W_hh fragments: A[row=gate-row g'][k=unit], rows permuted g'=4u+gate.
  // A-frag (16x16x32): lane l holds row (l&15), k = (l>>4)*8 + j  (j=0..7).
  half8 a0[16], a1[16];
  #pragma unroll
  for (int s2 = 0; s2 < 2; s2++) {
    const int gp = nb * 128 + (2 * w + s2) * 16 + ln;
    const int Rr = (gp & 3) * HH_ + (gp >> 2);
    const float* wp = Whh + (size_t)Rr * HH_;
    #pragma unroll
    for (int ks = 0; ks < 16; ks++) {
      const float* p = wp + ks * 32 + lg * 8;
      float4 f0 = ((const float4*)p)[0];
      float4 f1 = ((const float4*)p)[1];
      if (s2 == 0) a0[ks] = cvt8(f0, f1); else a1[ks] = cvt8(f0, f1);
    }
  }

  const int u0 = nb * 32 + (2 * w + 0) * 4 + lg;  // hidden unit of acc0's lane
  const int u1 = nb * 32 + (2 * w + 1) * 4 + lg;  // hidden unit of acc1's lane
  const int g0 = nb * 128 + (2 * w) * 16 + lg * 4; // first gate-row (i-gate) of u0

  float c0 = 0.f, c1 = 0.f;
  int* myflag = flags + bid * 32;
  int* watch = flags + (mg * 16 + (tid & 15)) * 32;
  const bool spinner = (tid < 16) && (tid != nb);

  for (int s = 1; s <= TT_; ++s) {
    const int t = s - 1;
    // prefetch gates_x for this step (independent of h)
    const _Float16* gxp = gx + (size_t)t * (BN_ * GG_) + (size_t)batch * GG_ + g0;
    uint2 ga = *(const uint2*)gxp;          // i,f,g,o preacts for u0
    uint2 gb = *(const uint2*)(gxp + 16);   // i,f,g,o preacts for u1

    // wait until all partners have published h_{s-1}
    if (spinner) {
      int guard = 0;
      while (__hip_atomic_load(watch, __ATOMIC_RELAXED, __HIP_MEMORY_SCOPE_AGENT) < s - 1) {
        __builtin_amdgcn_s_sleep(1);
        if (++guard > (1 << 20)) break;  // deadlock safety valve
      }
    }
    __threadfence();   // acquire: invalidate caches so h loads are fresh
    __syncthreads();

    // B-frag: B[k=unit][n=local batch] from hx[(s-1)&1][batch][unit]
    const _Float16* hin = hx + (size_t)(t & 1) * (BN_ * HH_) + (size_t)batch * HH_ + lg * 8;
    f32x4 acc0 = {0.f, 0.f, 0.f, 0.f}, acc1 = {0.f, 0.f, 0.f, 0.f};
    #pragma unroll
    for (int ks = 0; ks < 16; ks++) {
      half8 bfr = *(const half8*)(hin + ks * 32);
      acc0 = __builtin_amdgcn_mfma_f32_16x16x32_f16(a0[ks], bfr, acc0, 0, 0, 0);
      acc1 = __builtin_amdgcn_mfma_f32_16x16x32_f16(a1[ks], bfr, acc1, 0, 0, 0);
    }

    // lane-local cell update: acc regs = i,f,g,o preacts (recurrent part)
    union { uint2 u; _Float16 h[4]; } ua, ub;
    ua.u = ga; ub.u = gb;
    float iv = sigm(acc0[0] + (float)ua.h[0]);
    float fv = sigm(acc0[1] + (float)ua.h[1]);
    float gv = tanha(acc0[2] + (float)ua.h[2]);
    float ov = sigm(acc0[3] + (float)ua.h[3]);
    c0 = fv * c0 + iv * gv;
    const float h0 = ov * tanha(c0);

    iv = sigm(acc1[0] + (float)ub.h[0]);
    fv = sigm(acc1[1] + (float)ub.h[1]);
    gv = tanha(acc1[2] + (float)ub.h[2]);
    ov = sigm(acc1[3] + (float)ub.h[3]);
    c1 = fv * c1 + iv * gv;
    const float h1 = ov * tanha(c1);

    _Float16* hout = hx + (size_t)(s & 1) * (BN_ * HH_) + (size_t)batch * HH_;
    hout[u0] = (_Float16)h0;
    hout[u1] = (_Float16)h1;
    _Float16* hap = hall + (size_t)batch * (TT_ * HH_) + (size_t)t * HH_;
    hap[u0] = (_Float16)h0;
    hap[u1] = (_Float16)h1;

    __threadfence();   // release: push h stores device-wide
    __syncthreads();
    if (tid == 0)
      __hip_atomic_store(myflag, s, __ATOMIC_RELAXED, __HIP_MEMORY_SCOPE_AGENT);
  }
}

// ---------------------------------------------------------------------------
// Kernel 3: out[b][t][o] = h_all[b][t][:] @ fc_W.T + fc_b   (fp32 out)
// M=32768, N=256, K=512. Same tile structure as kernel 1.
// ---------------------------------------------------------------------------
__global__ __launch_bounds__(256) void fc_gemm_k(
    const _Float16* __restrict__ hall, const float* __restrict__ fcW,
    const float* __restrict__ fcb, float* __restrict__ out)
{
  __shared__ _Float16 As[128][40];
  __shared__ _Float16 Bs[128][40];
  const int bn = blockIdx.x & 1;
  const int bm = blockIdx.x >> 1;
  const int M0 = bm * 128, N0 = bn * 128;
  const int tid = threadIdx.x;
  const int w = tid >> 6, l = tid & 63, lg = l >> 4, ln = l & 15;
  const int wm = w & 1, wn = w >> 1;
  const int sr = tid >> 1, sp = tid & 1;

  f32x4 acc[4][4];
  #pragma unroll
  for (int i = 0; i < 4; i++) {
    #pragma unroll
    for (int j = 0; j < 4; j++) acc[i][j] = (f32x4){0.f, 0.f, 0.f, 0.f};
  }

  for (int K0 = 0; K0 < HH_; K0 += 32) {
    __syncthreads();
    {
      const _Float16* s0 = hall + (size_t)(M0 + sr) * HH_ + K0 + sp * 16;
      *(uint4*)&As[sr][sp * 16]     = ((const uint4*)s0)[0];
      *(uint4*)&As[sr][sp * 16 + 8] = ((const uint4*)s0)[1];
      const float* s1 = fcW + (size_t)(N0 + sr) * HH_ + K0 + sp * 16;
      float4 g0 = ((const float4*)s1)[0], g1 = ((const float4*)s1)[1];
      float4 g2 = ((const float4*)s1)[2], g3 = ((const float4*)s1)[3];
      *(half8*)&Bs[sr][sp * 16]     = cvt8(g0, g1);
      *(half8*)&Bs[sr][sp * 16 + 8] = cvt8(g2, g3);
    }
    __syncthreads();
    half8 af[4], bf[4];
    #pragma unroll
    for (int i = 0; i < 4; i++) af[i] = *(const half8*)&As[wm * 64 + i * 16 + ln][lg * 8];
    #pragma unroll
    for (int j = 0; j < 4; j++) bf[j] = *(const half8*)&Bs[wn * 64 + j * 16 + ln][lg * 8];
    #pragma unroll
    for (int i = 0; i < 4; i++) {
      #pragma unroll
      for (int j = 0; j < 4; j++)
        acc[i][j] = __builtin_amdgcn_mfma_f32_16x16x32_f16(af[i], bf[j], acc[i][j], 0, 0, 0);
    }
  }

  #pragma unroll
  for (int j = 0; j < 4; j++) {
    const int ncol = N0 + wn * 64 + j * 16 + ln;
    const float bias = fcb[ncol];
    #pragma unroll
    for (int i = 0; i < 4; i++) {
      #pragma unroll
      for (int rr = 0; rr < 4; rr++) {
        const int m = M0 + wm * 64 + i * 16 + lg * 4 + rr;
        out[(size_t)m * OO_ + ncol] = acc[i][j][rr] + bias;
      }
    }
  }
}

extern "C" void kernel_launch(void* const* d_in, const int* in_sizes, int n_in,
                              void* d_out, int out_size, void* d_ws, size_t ws_size,
                              hipStream_t stream) {
  (void)in_sizes; (void)n_in; (void)out_size;
  if (ws_size < WS_NEEDED) return;  // diagnostic: output stays zero -> absmax ~0.39

  const float* x   = (const float*)d_in[0];
  const float* Wih = (const float*)d_in[1];
  const float* Whh = (const float*)d_in[2];
  const float* bih = (const float*)d_in[3];
  const float* bhh = (const float*)d_in[4];
  const float* fcW = (const float*)d_in[5];
  const float* fcb = (const float*)d_in[6];
  float* out = (float*)d_out;

  char* ws = (char*)d_ws;
  _Float16* gx   = (_Float16*)(ws + GX_OFF);
  _Float16* hall = (_Float16*)(ws + HALL_OFF);
  _Float16* hx   = (_Float16*)(ws + HX_OFF);
  int* flags     = (int*)(ws + FLAG_OFF);

  // reset h0 = 0 and the step flags (must happen every call: replays reuse ws)
  (void)hipMemsetAsync(ws + HX_OFF, 0, HX_BYTES + FLAG_BYTES, stream);

  gates_gemm_k<<<dim3(4096), dim3(256), 0, stream>>>(x, Wih, bih, bhh, gx);
  lstm_rec_k<<<dim3(64), dim3(256), 0, stream>>>(Whh, gx, hall, hx, flags);
  fc_gemm_k<<<dim3(512), dim3(256), 0, stream>>>(hall, fcW, fcb, out);
}

// Round 2
// 2952.329 us; speedup vs baseline: 2.8364x; 2.8364x over previous
//
#include <hip/hip_runtime.h>
#include <stdint.h>

typedef _Float16 half8 __attribute__((ext_vector_type(8)));
typedef float f32x4 __attribute__((ext_vector_type(4)));

static constexpr int BN_ = 64;    // batch
static constexpr int TT_ = 512;   // time steps
static constexpr int II_ = 256;   // input dim
static constexpr int HH_ = 512;   // hidden dim
static constexpr int GG_ = 2048;  // 4*H
static constexpr int OO_ = 256;   // output dim

// workspace layout (bytes)
static constexpr size_t GX_OFF     = 0;
static constexpr size_t GX_BYTES   = (size_t)TT_ * BN_ * GG_ * 2;   // 128 MiB, fp16 [t][b][g']
static constexpr size_t HALL_OFF   = GX_OFF + GX_BYTES;
static constexpr size_t HALL_BYTES = (size_t)BN_ * TT_ * HH_ * 2;   // 32 MiB, fp16 [b][t][u]
static constexpr size_t HX_OFF     = HALL_OFF + HALL_BYTES;
static constexpr size_t HX_BYTES   = (size_t)2 * BN_ * HH_ * 2;     // h exchange, double buffered
static constexpr size_t FLAG_OFF   = HX_OFF + HX_BYTES;
static constexpr size_t FLAG_BYTES = (size_t)64 * 128;              // one 128B slot per block
static constexpr size_t WS_NEEDED  = FLAG_OFF + FLAG_BYTES;

__device__ __forceinline__ float sigm(float x)  { return 1.0f / (1.0f + __expf(-x)); }
__device__ __forceinline__ float tanha(float x) { return 1.0f - 2.0f / (__expf(2.0f * x) + 1.0f); }

__device__ __forceinline__ half8 cvt8(float4 a, float4 b) {
  half8 r;
  r[0]=(_Float16)a.x; r[1]=(_Float16)a.y; r[2]=(_Float16)a.z; r[3]=(_Float16)a.w;
  r[4]=(_Float16)b.x; r[5]=(_Float16)b.y; r[6]=(_Float16)b.z; r[7]=(_Float16)b.w;
  return r;
}

// ---------------------------------------------------------------------------
// Kernel 1: gates_x[t][b][g'] = (x @ W_ih.T)[b,t,R(g')] + b_ih[R] + b_hh[R]
// g' = 4*u + gate (permuted so the recurrence's 4 gates of unit u are adjacent)
// R(g') = (g'&3)*512 + (g'>>2)  (original row in W_ih / biases)
// M=32768 (m=b*512+t), N=2048, K=256. 128x128 tile, BK=32, 4 waves.
// ---------------------------------------------------------------------------
__global__ __launch_bounds__(256) void gates_gemm_k(
    const float* __restrict__ x, const float* __restrict__ Wih,
    const float* __restrict__ bih, const float* __restrict__ bhh,
    _Float16* __restrict__ gx)
{
  __shared__ _Float16 As[128][40];  // [m][k] fp16, +8 pad
  __shared__ _Float16 Bs[128][40];  // [n][k] fp16 (B transposed), +8 pad
  const int bn = blockIdx.x & 15;
  const int bm = blockIdx.x >> 4;
  const int M0 = bm * 128, N0 = bn * 128;
  const int tid = threadIdx.x;
  const int w = tid >> 6, l = tid & 63, lg = l >> 4, ln = l & 15;
  const int wm = w & 1, wn = w >> 1;
  const int sr = tid >> 1, sp = tid & 1;  // staging row / half-row
  const int nglob = N0 + sr;
  const int Rrow = (nglob & 3) * HH_ + (nglob >> 2);

  f32x4 acc[4][4];
  #pragma unroll
  for (int i = 0; i < 4; i++) {
    #pragma unroll
    for (int j = 0; j < 4; j++) acc[i][j] = (f32x4){0.f, 0.f, 0.f, 0.f};
  }

  for (int K0 = 0; K0 < II_; K0 += 32) {
    __syncthreads();
    {
      const float* s0 = x + (size_t)(M0 + sr) * II_ + K0 + sp * 16;
      float4 f0 = ((const float4*)s0)[0], f1 = ((const float4*)s0)[1];
      float4 f2 = ((const float4*)s0)[2], f3 = ((const float4*)s0)[3];
      *(half8*)&As[sr][sp * 16]     = cvt8(f0, f1);
      *(half8*)&As[sr][sp * 16 + 8] = cvt8(f2, f3);
      const float* s1 = Wih + (size_t)Rrow * II_ + K0 + sp * 16;
      float4 g0 = ((const float4*)s1)[0], g1 = ((const float4*)s1)[1];
      float4 g2 = ((const float4*)s1)[2], g3 = ((const float4*)s1)[3];
      *(half8*)&Bs[sr][sp * 16]     = cvt8(g0, g1);
      *(half8*)&Bs[sr][sp * 16 + 8] = cvt8(g2, g3);
    }
    __syncthreads();
    half8 af[4], bf[4];
    #pragma unroll
    for (int i = 0; i < 4; i++) af[i] = *(const half8*)&As[wm * 64 + i * 16 + ln][lg * 8];
    #pragma unroll
    for (int j = 0; j < 4; j++) bf[j] = *(const half8*)&Bs[wn * 64 + j * 16 + ln][lg * 8];
    #pragma unroll
    for (int i = 0; i < 4; i++) {
      #pragma unroll
      for (int j = 0; j < 4; j++)
        acc[i][j] = __builtin_amdgcn_mfma_f32_16x16x32_f16(af[i], bf[j], acc[i][j], 0, 0, 0);
    }
  }

  #pragma unroll
  for (int j = 0; j < 4; j++) {
    const int ncol = N0 + wn * 64 + j * 16 + ln;
    const int R = (ncol & 3) * HH_ + (ncol >> 2);
    const float bias = bih[R] + bhh[R];
    #pragma unroll
    for (int i = 0; i < 4; i++) {
      #pragma unroll
      for (int rr = 0; rr < 4; rr++) {
        const int m = M0 + wm * 64 + i * 16 + lg * 4 + rr;
        const int bb = m >> 9, tt = m & 511;  // m = b*512 + t
        gx[(size_t)tt * (BN_ * GG_) + (size_t)bb * GG_ + ncol] =
            (_Float16)(acc[i][j][rr] + bias);
      }
    }
  }
}

// ---------------------------------------------------------------------------
// Kernel 2: persistent LSTM recurrence.
// 64 blocks = 4 batch-groups (16 batches each) x 16 unit-slices (32 units each).
// W_hh fragments resident in VGPRs. Cross-block h exchange goes through the
// COHERENCE POINT (system-scope relaxed atomics: stores write through, loads
// bypass L1/L2) — no threadfence, no buffer_wbl2/inv L2 flush storms.
// Release ordering: s_waitcnt vmcnt(0) before the flag store.
// ---------------------------------------------------------------------------
__global__ __launch_bounds__(256, 1) void lstm_rec_k(
    const float* __restrict__ Whh, const _Float16* __restrict__ gx,
    _Float16* __restrict__ hall, _Float16* __restrict__ hx,
    int* __restrict__ flags)
{
  const int bid = blockIdx.x;
  const int mg = bid >> 4, nb = bid & 15;
  const int tid = threadIdx.x;
  const int w = tid >> 6, l = tid & 63, lg = l >> 4, ln = l & 15;
  const int batch = mg * 16 + ln;

  // Preload W_hh fragments: A[row=gate-row g'][k=unit], rows permuted g'=4u+gate.
  // A-frag (16x16x32): lane l holds row (l&15), k = (l>>4)*8 + j  (j=0..7).
  half8 a0[16], a1[16];
  #pragma unroll
  for (int s2 = 0; s2 < 2; s2++) {
    const int gp = nb * 128 + (2 * w + s2) * 16 + ln;
    const int Rr = (gp & 3) * HH_ + (gp >> 2);
    const float* wp = Whh + (size_t)Rr * HH_;
    #pragma unroll
    for (int ks = 0; ks < 16; ks++) {
      const float* p = wp + ks * 32 + lg * 8;
      float4 f0 = ((const float4*)p)[0];
      float4 f1 = ((const float4*)p)[1];
      if (s2 == 0) a0[ks] = cvt8(f0, f1); else a1[ks] = cvt8(f0, f1);
    }
  }

  const int u0 = nb * 32 + (2 * w + 0) * 4 + lg;  // hidden unit of acc0's lane
  const int u1 = nb * 32 + (2 * w + 1) * 4 + lg;  // hidden unit of acc1's lane
  const int g0 = nb * 128 + (2 * w) * 16 + lg * 4; // first gate-row (i-gate) of u0

  float c0 = 0.f, c1 = 0.f;
  int* myflag = flags + bid * 32;
  int* watch = flags + (mg * 16 + (tid & 15)) * 32;
  const bool spinner = (tid < 16) && (tid != nb);

  for (int s = 1; s <= TT_; ++s) {
    const int t = s - 1;
    // prefetch gates_x for this step (independent of h, normal cached loads)
    const _Float16* gxp = gx + (size_t)t * (BN_ * GG_) + (size_t)batch * GG_ + g0;
    uint2 ga = *(const uint2*)gxp;          // i,f,g,o preacts for u0
    uint2 gb = *(const uint2*)(gxp + 16);   // i,f,g,o preacts for u1

    // wait until all partners have published h_{s-1} (flag >= s-1 also
    // guarantees they finished READING h_{s-2}, so overwriting parity s&1 is safe)
    if (spinner) {
      int guard = 0;
      while (__hip_atomic_load(watch, __ATOMIC_RELAXED, __HIP_MEMORY_SCOPE_SYSTEM) < s - 1) {
        if (++guard > (1 << 20)) break;  // deadlock safety valve
      }
    }
    __syncthreads();

    // B-frag: B[k=unit][n=local batch] from hx[(s-1)&1][batch][unit].
    // Loads bypass L1/L2 (system-scope relaxed) -> read the coherence point.
    const unsigned long long* hin64 = (const unsigned long long*)(
        hx + (size_t)(t & 1) * (BN_ * HH_) + (size_t)batch * HH_);
    unsigned long long hw[32];
    #pragma unroll
    for (int ks = 0; ks < 16; ks++) {
      const int e = (lg * 8 + ks * 32) >> 2;  // b64 index (4 fp16 per word)
      hw[2 * ks]     = __hip_atomic_load(&hin64[e],     __ATOMIC_RELAXED, __HIP_MEMORY_SCOPE_SYSTEM);
      hw[2 * ks + 1] = __hip_atomic_load(&hin64[e + 1], __ATOMIC_RELAXED, __HIP_MEMORY_SCOPE_SYSTEM);
    }

    f32x4 acc0 = {0.f, 0.f, 0.f, 0.f}, acc1 = {0.f, 0.f, 0.f, 0.f};
    #pragma unroll
    for (int ks = 0; ks < 16; ks++) {
      union { unsigned long long q[2]; half8 h; } ub_;
      ub_.q[0] = hw[2 * ks]; ub_.q[1] = hw[2 * ks + 1];
      acc0 = __builtin_amdgcn_mfma_f32_16x16x32_f16(a0[ks], ub_.h, acc0, 0, 0, 0);
      acc1 = __builtin_amdgcn_mfma_f32_16x16x32_f16(a1[ks], ub_.h, acc1, 0, 0, 0);
    }

    // lane-local cell update: acc regs = i,f,g,o preacts (recurrent part)
    union { uint2 u; _Float16 h[4]; } ua, ub;
    ua.u = ga; ub.u = gb;
    float iv = sigm(acc0[0] + (float)ua.h[0]);
    float fv = sigm(acc0[1] + (float)ua.h[1]);
    float gv = tanha(acc0[2] + (float)ua.h[2]);
    float ov = sigm(acc0[3] + (float)ua.h[3]);
    c0 = fv * c0 + iv * gv;
    const float h0 = ov * tanha(c0);

    iv = sigm(acc1[0] + (float)ub.h[0]);
    fv = sigm(acc1[1] + (float)ub.h[1]);
    gv = tanha(acc1[2] + (float)ub.h[2]);
    ov = sigm(acc1[3] + (float)ub.h[3]);
    c1 = fv * c1 + iv * gv;
    const float h1 = ov * tanha(c1);

    // publish h: write-through to coherence point (no cache flush needed)
    unsigned short* hout = (unsigned short*)(hx + (size_t)(s & 1) * (BN_ * HH_) + (size_t)batch * HH_);
    union { _Float16 f; unsigned short us; } cv0, cv1;
    cv0.f = (_Float16)h0; cv1.f = (_Float16)h1;
    __hip_atomic_store(&hout[u0], cv0.us, __ATOMIC_RELAXED, __HIP_MEMORY_SCOPE_SYSTEM);
    __hip_atomic_store(&hout[u1], cv1.us, __ATOMIC_RELAXED, __HIP_MEMORY_SCOPE_SYSTEM);
    // hall: normal cached store (consumed by next dispatch; boundary handles coherence)
    _Float16* hap = hall + (size_t)batch * (TT_ * HH_) + (size_t)t * HH_;
    hap[u0] = (_Float16)h0;
    hap[u1] = (_Float16)h1;

    asm volatile("s_waitcnt vmcnt(0)" ::: "memory");  // release: h stores performed
    __syncthreads();                                   // all waves of block done
    if (tid == 0)
      __hip_atomic_store(myflag, s, __ATOMIC_RELAXED, __HIP_MEMORY_SCOPE_SYSTEM);
  }
}

// ---------------------------------------------------------------------------
// Kernel 3: out[b][t][o] = h_all[b][t][:] @ fc_W.T + fc_b   (fp32 out)
// M=32768, N=256, K=512. Same tile structure as kernel 1.
// ---------------------------------------------------------------------------
__global__ __launch_bounds__(256) void fc_gemm_k(
    const _Float16* __restrict__ hall, const float* __restrict__ fcW,
    const float* __restrict__ fcb, float* __restrict__ out)
{
  __shared__ _Float16 As[128][40];
  __shared__ _Float16 Bs[128][40];
  const int bn = blockIdx.x & 1;
  const int bm = blockIdx.x >> 1;
  const int M0 = bm * 128, N0 = bn * 128;
  const int tid = threadIdx.x;
  const int w = tid >> 6, l = tid & 63, lg = l >> 4, ln = l & 15;
  const int wm = w & 1, wn = w >> 1;
  const int sr = tid >> 1, sp = tid & 1;

  f32x4 acc[4][4];
  #pragma unroll
  for (int i = 0; i < 4; i++) {
    #pragma unroll
    for (int j = 0; j < 4; j++) acc[i][j] = (f32x4){0.f, 0.f, 0.f, 0.f};
  }

  for (int K0 = 0; K0 < HH_; K0 += 32) {
    __syncthreads();
    {
      const _Float16* s0 = hall + (size_t)(M0 + sr) * HH_ + K0 + sp * 16;
      *(uint4*)&As[sr][sp * 16]     = ((const uint4*)s0)[0];
      *(uint4*)&As[sr][sp * 16 + 8] = ((const uint4*)s0)[1];
      const float* s1 = fcW + (size_t)(N0 + sr) * HH_ + K0 + sp * 16;
      float4 g0 = ((const float4*)s1)[0], g1 = ((const float4*)s1)[1];
      float4 g2 = ((const float4*)s1)[2], g3 = ((const float4*)s1)[3];
      *(half8*)&Bs[sr][sp * 16]     = cvt8(g0, g1);
      *(half8*)&Bs[sr][sp * 16 + 8] = cvt8(g2, g3);
    }
    __syncthreads();
    half8 af[4], bf[4];
    #pragma unroll
    for (int i = 0; i < 4; i++) af[i] = *(const half8*)&As[wm * 64 + i * 16 + ln][lg * 8];
    #pragma unroll
    for (int j = 0; j < 4; j++) bf[j] = *(const half8*)&Bs[wn * 64 + j * 16 + ln][lg * 8];
    #pragma unroll
    for (int i = 0; i < 4; i++) {
      #pragma unroll
      for (int j = 0; j < 4; j++)
        acc[i][j] = __builtin_amdgcn_mfma_f32_16x16x32_f16(af[i], bf[j], acc[i][j], 0, 0, 0);
    }
  }

  #pragma unroll
  for (int j = 0; j < 4; j++) {
    const int ncol = N0 + wn * 64 + j * 16 + ln;
    const float bias = fcb[ncol];
    #pragma unroll
    for (int i = 0; i < 4; i++) {
      #pragma unroll
      for (int rr = 0; rr < 4; rr++) {
        const int m = M0 + wm * 64 + i * 16 + lg * 4 + rr;
        out[(size_t)m * OO_ + ncol] = acc[i][j][rr] + bias;
      }
    }
  }
}

extern "C" void kernel_launch(void* const* d_in, const int* in_sizes, int n_in,
                              void* d_out, int out_size, void* d_ws, size_t ws_size,
                              hipStream_t stream) {
  (void)in_sizes; (void)n_in; (void)out_size;
  if (ws_size < WS_NEEDED) return;  // diagnostic: output stays zero -> absmax ~0.39

  const float* x   = (const float*)d_in[0];
  const float* Wih = (const float*)d_in[1];
  const float* Whh = (const float*)d_in[2];
  const float* bih = (const float*)d_in[3];
  const float* bhh = (const float*)d_in[4];
  const float* fcW = (const float*)d_in[5];
  const float* fcb = (const float*)d_in[6];
  float* out = (float*)d_out;

  char* ws = (char*)d_ws;
  _Float16* gx   = (_Float16*)(ws + GX_OFF);
  _Float16* hall = (_Float16*)(ws + HALL_OFF);
  _Float16* hx   = (_Float16*)(ws + HX_OFF);
  int* flags     = (int*)(ws + FLAG_OFF);

  // reset h0 = 0 and the step flags (must happen every call: replays reuse ws)
  (void)hipMemsetAsync(ws + HX_OFF, 0, HX_BYTES + FLAG_BYTES, stream);

  gates_gemm_k<<<dim3(4096), dim3(256), 0, stream>>>(x, Wih, bih, bhh, gx);
  lstm_rec_k<<<dim3(64), dim3(256), 0, stream>>>(Whh, gx, hall, hx, flags);
  fc_gemm_k<<<dim3(512), dim3(256), 0, stream>>>(hall, fcW, fcb, out);
}